// Round 17
// baseline (98.817 us; speedup 1.0000x reference)
//
#include <hip/hip_runtime.h>
#include <hip/hip_bf16.h>
#include <stdint.h>

#define NN 8192
#define CC 256
#define NSPLIT 8                          // j-splits; h = blk&7 == XCD id
#define JR (NN / NSPLIT)                  // 1024 j per split
#define NITER (JR / 32)                   // 32 chunks of 32 j

typedef float f32x4 __attribute__((ext_vector_type(4)));
typedef float f32x2 __attribute__((ext_vector_type(2)));
typedef short s16x8 __attribute__((ext_vector_type(8)));

#define LOG2E 1.4426950408889634f

// ---- workspace layout (float offsets). Total ~46.4 MB. ----
#define OFF_WT  0                                 // 256*256 transposed w_reduce
#define OFF_R   (OFF_WT + CC*CC)                  // N*C fp32 r
#define OFF_S2  (OFF_R + NN*CC)                   // N fp32 s*log2e
#define OFF_C0  (OFF_S2 + NN)                     // [0]=c0, [1]=c0*log2e
#define OFF_SS  (OFF_C0 + 16)                     // NSPLIT*N fp32 partial row-sums of Z
#define OFF_SP  (OFF_SS + NSPLIT*NN)              // 4*N fp32 s partials (per colblk)
#define OFF_V   (OFF_SP + 4*NN)                   // NSPLIT*N*C bf16 partial Z@r (ushort)
#define OFF_RB  (OFF_V + (NSPLIT*NN*CC)/2)        // N*C bf16 (ushort) fragment-ordered r

// ---------------- kernel 1: transpose Wr + compute c0 ----------------
__global__ __launch_bounds__(256) void k_prep(const float* __restrict__ w,
                                              const float* __restrict__ br,
                                              const float* __restrict__ wcv,
                                              const float* __restrict__ bc,
                                              float* __restrict__ ws) {
  int k = blockIdx.x, c = threadIdx.x;
  ws[OFF_WT + k * CC + c] = w[c * CC + k];   // wT[k][c] = w[c][k]
  if (blockIdx.x == 0 && threadIdx.x < 64) {
    int lane = threadIdx.x;
    f32x4 b4 = *(const f32x4*)&br[lane * 4];
    f32x4 w4 = *(const f32x4*)&wcv[lane * 4];
    float d = b4[0]*w4[0] + b4[1]*w4[1] + b4[2]*w4[2] + b4[3]*w4[3];
    #pragma unroll
    for (int m = 32; m >= 1; m >>= 1) d += __shfl_xor(d, m, 64);
    if (lane == 0) { ws[OFF_C0] = d + bc[0]; ws[OFF_C0 + 1] = (d + bc[0]) * LOG2E; }
  }
}

// ---------------- kernel 2: r = x @ Wr^T + rb (u64 frag stores) + s partials --
__global__ __launch_bounds__(256) void k_r(const float* __restrict__ x,
                                           const float* __restrict__ wcv,
                                           float* __restrict__ ws) {
  __shared__ float xs[64][260];
  int bi = blockIdx.x;
  int rowblk = bi >> 2, colblk = bi & 3;
  int tid = threadIdx.x;
  int i0 = rowblk * 64;
  for (int t = tid; t < 64 * 64; t += 256) {
    int rr = t >> 6, c4 = t & 63;
    *(f32x4*)&xs[rr][c4 * 4] = *(const f32x4*)&x[(i0 + rr) * CC + c4 * 4];
  }
  __syncthreads();
  int tx = tid & 15, ty = tid >> 4;
  int cbase = colblk * 64 + tx * 4;
  int r0 = ty * 4;
  float acc[4][4] = {};
  const float* wt = ws + OFF_WT;
  for (int k = 0; k < CC; k += 2) {
    f32x4 wv0 = *(const f32x4*)&wt[k * CC + cbase];
    f32x4 wv1 = *(const f32x4*)&wt[(k + 1) * CC + cbase];
    f32x2 xv[4];
    #pragma unroll
    for (int rr = 0; rr < 4; rr++) xv[rr] = *(const f32x2*)&xs[r0 + rr][k];
    #pragma unroll
    for (int rr = 0; rr < 4; rr++)
      #pragma unroll
      for (int cc = 0; cc < 4; cc++)
        acc[rr][cc] = fmaf(xv[rr][1], wv1[cc], fmaf(xv[rr][0], wv0[cc], acc[rr][cc]));
  }
  #pragma unroll
  for (int rr = 0; rr < 4; rr++) {
    f32x4 o = {acc[rr][0], acc[rr][1], acc[rr][2], acc[rr][3]};
    *(f32x4*)&ws[OFF_R + (size_t)(i0 + r0 + rr) * CC + cbase] = o;
  }
  // rb fragment-order u64 stores (proven mapping)
  unsigned long long* rb64 = (unsigned long long*)(ws + OFF_RB);
  int j0r = i0 + r0;                          // j0r&7 in {0,4}
  #pragma unroll
  for (int cc = 0; cc < 4; cc++) {
    int c = cbase + cc;
    unsigned long long v = 0;
    #pragma unroll
    for (int rr = 0; rr < 4; rr++) {
      unsigned u = __float_as_uint(acc[rr][cc]);
      u = (u + 0x7fffu + ((u >> 16) & 1u)) >> 16;   // RNE to bf16
      v |= (unsigned long long)u << (16 * rr);
    }
    int us = (((j0r >> 5) * 16 + (c >> 4)) * 64 + (((j0r >> 3) & 3) * 16 + (c & 15))) * 8 + (j0r & 7);
    rb64[us >> 2] = v;                        // us % 4 == 0
  }
  // s partials: this block's 64-col contribution, shuffle-reduced over tx
  f32x4 wc4 = *(const f32x4*)&wcv[cbase];
  float sd[4];
  #pragma unroll
  for (int rr = 0; rr < 4; rr++) {
    sd[rr] = acc[rr][0]*wc4[0] + acc[rr][1]*wc4[1] + acc[rr][2]*wc4[2] + acc[rr][3]*wc4[3];
    #pragma unroll
    for (int m = 1; m < 16; m <<= 1) sd[rr] += __shfl_xor(sd[rr], m, 64);
  }
  if (tx == 0) {
    #pragma unroll
    for (int rr = 0; rr < 4; rr++)
      ws[OFF_SP + colblk * NN + j0r + rr] = sd[rr];
  }
}

// ---------------- kernel 3: s2 = (sum of 4 partials) * log2e ----------------
__global__ __launch_bounds__(256) void k_s2(float* __restrict__ ws) {
  int row = blockIdx.x * 256 + threadIdx.x;   // 32 blocks
  float s = ws[OFF_SP + row] + ws[OFF_SP + NN + row]
          + ws[OFF_SP + 2 * NN + row] + ws[OFF_SP + 3 * NN + row];
  ws[OFF_S2 + row] = s * LOG2E;
}

// ---------------- kernel 4: main pairwise flash-style kernel ----------------
// FAT WAVES: 512 blocks x 128 threads = 64 row-tiles (128 rows: 2 waves x 64)
// x 8 j-splits. Each wave owns 4 row-fragments -> one B ds_read feeds 4 MFMAs
// (halves LDS port traffic vs 2-frag). Depth-1 WAITBAR0 loop (R13-proven),
// acc[4][16]+cvt_pk SIG+VALU ssum (R6-proven). 36 KB LDS -> 2 blocks/CU.

union U8 { s16x8 v; unsigned u[4]; };

#define STAGE(BUF, IT) { \
  const char* gb_ = rbase + (size_t)(IT) * 16384 + w * 1024 + l * 16; \
  _Pragma("unroll") \
  for (int q_ = 0; q_ < 8; q_++) \
    __builtin_amdgcn_global_load_lds( \
      (const __attribute__((address_space(1))) void*)(gb_ + q_ * 2048), \
      (__attribute__((address_space(3))) void*)&ldsb[(BUF) * 16384 + w * 1024 + q_ * 2048 + l * 16], \
      16, 0, 0); }

#define WAITBAR0 { asm volatile("s_waitcnt vmcnt(0)" ::: "memory"); \
  __builtin_amdgcn_s_barrier(); \
  __builtin_amdgcn_sched_barrier(0); }

#define SB0 __builtin_amdgcn_sched_barrier(0);

// sigmoids for 4 row-frags x 32 j; accumulates ssum; cvt_pk packs bf16
#define SIG4(IT, AF) { \
  f32x4 a0_ = *(const f32x4*)&s2l[(IT) * 32 + g * 8]; \
  f32x4 a1_ = *(const f32x4*)&s2l[(IT) * 32 + g * 8 + 4]; \
  _Pragma("unroll") \
  for (int f_ = 0; f_ < 4; f_++) { \
    float z_[8]; \
    _Pragma("unroll") \
    for (int t_ = 0; t_ < 8; t_++) { \
      float sj_ = (t_ < 4) ? a0_[t_] : a1_[t_ - 4]; \
      float e_; \
      asm("v_exp_f32 %0, %1" : "=v"(e_) : "v"(nega[f_] - sj_)); \
      float zz_ = __builtin_amdgcn_rcpf(1.0f + e_); \
      ssum[f_] += zz_; \
      z_[t_] = zz_; \
    } \
    U8 u8_; \
    asm("v_cvt_pk_bf16_f32 %0, %1, %2" : "=v"(u8_.u[0]) : "v"(z_[0]), "v"(z_[1])); \
    asm("v_cvt_pk_bf16_f32 %0, %1, %2" : "=v"(u8_.u[1]) : "v"(z_[2]), "v"(z_[3])); \
    asm("v_cvt_pk_bf16_f32 %0, %1, %2" : "=v"(u8_.u[2]) : "v"(z_[4]), "v"(z_[5])); \
    asm("v_cvt_pk_bf16_f32 %0, %1, %2" : "=v"(u8_.u[3]) : "v"(z_[6]), "v"(z_[7])); \
    AF[f_] = u8_.v; \
  } }

#define MF4(AF, LP) { \
  _Pragma("unroll") \
  for (int ct_ = 0; ct_ < 16; ct_++) { \
    s16x8 bf_ = *(const s16x8*)((LP) + ct_ * 1024 + l * 16); \
    _Pragma("unroll") \
    for (int f_ = 0; f_ < 4; f_++) \
      acc[f_][ct_] = __builtin_amdgcn_mfma_f32_16x16x32_bf16(AF[f_], bf_, acc[f_][ct_], 0, 0, 0); \
  } }

__global__ __launch_bounds__(128, 1) void k_main(float* __restrict__ ws) {
  __shared__ char ldsb[2 * 16384];
  __shared__ float s2l[JR];
  int blk = blockIdx.x;
  int rt = blk >> 3, h = blk & 7;            // h == XCD id -> per-XCD L2 locality
  int tid = threadIdx.x;                     // 0..127
  int w = tid >> 6, l = tid & 63;
  int lr = l & 15, g = l >> 4;
  int iw = rt * 128 + w * 64;                // wave's 64-row strip (4 frags of 16)
  float c02 = ws[OFF_C0 + 1];
  float nega[4];
  #pragma unroll
  for (int f = 0; f < 4; f++)
    nega[f] = -(ws[OFF_S2 + iw + f * 16 + lr] + c02);

  // stage this split's s2 slice to LDS (keeps loop VMEM = global_load_lds only)
  const float* s2p = ws + OFF_S2 + h * JR;
  *(f32x4*)&s2l[tid * 4] = *(const f32x4*)(s2p + tid * 4);
  *(f32x4*)&s2l[(tid + 128) * 4] = *(const f32x4*)(s2p + (tid + 128) * 4);
  __syncthreads();

  f32x4 acc[4][16];
  #pragma unroll
  for (int f = 0; f < 4; f++)
    #pragma unroll
    for (int ct = 0; ct < 16; ct++) acc[f][ct] = (f32x4)(0.f);
  float ssum[4] = {0.f, 0.f, 0.f, 0.f};

  const char* rbase = (const char*)(ws + OFF_RB) + (size_t)h * (JR * CC * 2);

  STAGE(0, 0);
  s16x8 af[4];
  #pragma unroll 1
  for (int J = 0; J < NITER; ++J) {
    WAITBAR0;                                // buf J ready; prev readers done
    if (J + 1 < NITER) STAGE((J + 1) & 1, J + 1);
    SB0;
    SIG4(J, af);                             // exactly once per chunk
    MF4(af, ldsb + (J & 1) * 16384);
  }

  // row-sums of Z: lanes {l, l^16, l^32, l^48} share row lr within a frag
  #pragma unroll
  for (int f = 0; f < 4; f++) {
    ssum[f] += __shfl_xor(ssum[f], 16, 64);
    ssum[f] += __shfl_xor(ssum[f], 32, 64);
  }
  if (l < 16) {
    #pragma unroll
    for (int f = 0; f < 4; f++)
      ws[OFF_SS + h * NN + iw + f * 16 + lr] = ssum[f];
  }
  // V partials (bf16). C/D layout: col = lane&15, row = (lane>>4)*4 + reg
  unsigned short* Vb = (unsigned short*)(ws + OFF_V);
  size_t vbase = (size_t)h * (NN * CC);
  #pragma unroll
  for (int f = 0; f < 4; f++)
    #pragma unroll
    for (int ct = 0; ct < 16; ct++)
      #pragma unroll
      for (int q = 0; q < 4; q++) {
        unsigned u = __float_as_uint(acc[f][ct][q]);
        u = (u + 0x7fffu + ((u >> 16) & 1u)) >> 16;
        Vb[vbase + (size_t)(iw + f * 16 + g * 4 + q) * CC + ct * 16 + lr] = (unsigned short)u;
      }
}

// ---------------- kernel 5: epilogue out = (r+b)*S/N + sum_h V_h/N ----------
__global__ __launch_bounds__(256) void k_epi(const float* __restrict__ br,
                                             const float* __restrict__ ws,
                                             float* __restrict__ out) {
  int idx = blockIdx.x * 256 + threadIdx.x;   // N*C/8 = 262144 threads
  int i = idx >> 5, c8 = (idx & 31) * 8;
  float S = 0.f;
  #pragma unroll
  for (int p = 0; p < NSPLIT; p++) S += ws[OFF_SS + p * NN + i];
  float m = S * (1.0f / NN);
  float v[8] = {};
  const unsigned short* Vb = (const unsigned short*)(ws + OFF_V);
  #pragma unroll
  for (int p = 0; p < NSPLIT; p++) {
    s16x8 pv = *(const s16x8*)&Vb[(size_t)p * (NN * CC) + (size_t)i * CC + c8];
    #pragma unroll
    for (int t = 0; t < 8; t++)
      v[t] += __uint_as_float(((unsigned)(unsigned short)pv[t]) << 16);
  }
  f32x4 r0 = *(const f32x4*)&ws[OFF_R + (size_t)i * CC + c8];
  f32x4 r1 = *(const f32x4*)&ws[OFF_R + (size_t)i * CC + c8 + 4];
  f32x4 b0 = *(const f32x4*)&br[c8];
  f32x4 b1 = *(const f32x4*)&br[c8 + 4];
  f32x4 o0, o1;
  #pragma unroll
  for (int t = 0; t < 4; t++) {
    o0[t] = (r0[t] + b0[t]) * m + v[t] * (1.0f / NN);
    o1[t] = (r1[t] + b1[t]) * m + v[t + 4] * (1.0f / NN);
  }
  *(f32x4*)&out[(size_t)i * CC + c8] = o0;
  *(f32x4*)&out[(size_t)i * CC + c8 + 4] = o1;
}

extern "C" void kernel_launch(void* const* d_in, const int* in_sizes, int n_in,
                              void* d_out, int out_size, void* d_ws, size_t ws_size,
                              hipStream_t stream) {
  const float* x  = (const float*)d_in[0];
  const float* w  = (const float*)d_in[1];
  const float* br = (const float*)d_in[2];
  const float* wc = (const float*)d_in[3];
  const float* bc = (const float*)d_in[4];
  float* ws = (float*)d_ws;
  float* out = (float*)d_out;
  (void)in_sizes; (void)n_in; (void)out_size; (void)ws_size;

  k_prep<<<256, 256, 0, stream>>>(w, br, wc, bc, ws);
  k_r<<<512, 256, 0, stream>>>(x, wc, ws);
  k_s2<<<32, 256, 0, stream>>>(ws);
  k_main<<<512, 128, 0, stream>>>(ws);
  k_epi<<<1024, 256, 0, stream>>>(br, ws, out);
}

// Round 18
// 84.636 us; speedup vs baseline: 1.1676x; 1.1676x over previous
//
#include <hip/hip_runtime.h>
#include <hip/hip_bf16.h>
#include <stdint.h>

#define NN 8192
#define CC 256
#define NSPLIT 8                          // j-splits; h = blk&7 == XCD id
#define JR (NN / NSPLIT)                  // 1024 j per split
#define NITER (JR / 32)                   // 32 chunks of 32 j

typedef float f32x4 __attribute__((ext_vector_type(4)));
typedef float f32x2 __attribute__((ext_vector_type(2)));
typedef short s16x8 __attribute__((ext_vector_type(8)));

#define LOG2E 1.4426950408889634f

// ---- workspace layout (float offsets). Total ~46.4 MB. ----
#define OFF_WT  0                                 // 256*256 transposed w_reduce
#define OFF_R   (OFF_WT + CC*CC)                  // N*C fp32 r
#define OFF_S2  (OFF_R + NN*CC)                   // N fp32 s*log2e
#define OFF_C0  (OFF_S2 + NN)                     // [0]=c0, [1]=c0*log2e
#define OFF_SS  (OFF_C0 + 16)                     // NSPLIT*N fp32 partial row-sums of Z
#define OFF_SP  (OFF_SS + NSPLIT*NN)              // 4*N fp32 s partials (per colblk)
#define OFF_V   (OFF_SP + 4*NN)                   // NSPLIT*N*C bf16 partial Z@r (ushort)
#define OFF_RB  (OFF_V + (NSPLIT*NN*CC)/2)        // N*C bf16 (ushort) fragment-ordered r

// ---------------- kernel 1: transpose Wr + compute c0 ----------------
__global__ __launch_bounds__(256) void k_prep(const float* __restrict__ w,
                                              const float* __restrict__ br,
                                              const float* __restrict__ wcv,
                                              const float* __restrict__ bc,
                                              float* __restrict__ ws) {
  int k = blockIdx.x, c = threadIdx.x;
  ws[OFF_WT + k * CC + c] = w[c * CC + k];   // wT[k][c] = w[c][k]
  if (blockIdx.x == 0 && threadIdx.x < 64) {
    int lane = threadIdx.x;
    f32x4 b4 = *(const f32x4*)&br[lane * 4];
    f32x4 w4 = *(const f32x4*)&wcv[lane * 4];
    float d = b4[0]*w4[0] + b4[1]*w4[1] + b4[2]*w4[2] + b4[3]*w4[3];
    #pragma unroll
    for (int m = 32; m >= 1; m >>= 1) d += __shfl_xor(d, m, 64);
    if (lane == 0) { ws[OFF_C0] = d + bc[0]; ws[OFF_C0 + 1] = (d + bc[0]) * LOG2E; }
  }
}

// ---------------- kernel 2: r = x @ Wr^T + rb (u64 frag stores) + s partials --
__global__ __launch_bounds__(256) void k_r(const float* __restrict__ x,
                                           const float* __restrict__ wcv,
                                           float* __restrict__ ws) {
  __shared__ float xs[64][260];
  int bi = blockIdx.x;
  int rowblk = bi >> 2, colblk = bi & 3;
  int tid = threadIdx.x;
  int i0 = rowblk * 64;
  for (int t = tid; t < 64 * 64; t += 256) {
    int rr = t >> 6, c4 = t & 63;
    *(f32x4*)&xs[rr][c4 * 4] = *(const f32x4*)&x[(i0 + rr) * CC + c4 * 4];
  }
  __syncthreads();
  int tx = tid & 15, ty = tid >> 4;
  int cbase = colblk * 64 + tx * 4;
  int r0 = ty * 4;
  float acc[4][4] = {};
  const float* wt = ws + OFF_WT;
  for (int k = 0; k < CC; k += 2) {
    f32x4 wv0 = *(const f32x4*)&wt[k * CC + cbase];
    f32x4 wv1 = *(const f32x4*)&wt[(k + 1) * CC + cbase];
    f32x2 xv[4];
    #pragma unroll
    for (int rr = 0; rr < 4; rr++) xv[rr] = *(const f32x2*)&xs[r0 + rr][k];
    #pragma unroll
    for (int rr = 0; rr < 4; rr++)
      #pragma unroll
      for (int cc = 0; cc < 4; cc++)
        acc[rr][cc] = fmaf(xv[rr][1], wv1[cc], fmaf(xv[rr][0], wv0[cc], acc[rr][cc]));
  }
  #pragma unroll
  for (int rr = 0; rr < 4; rr++) {
    f32x4 o = {acc[rr][0], acc[rr][1], acc[rr][2], acc[rr][3]};
    *(f32x4*)&ws[OFF_R + (size_t)(i0 + r0 + rr) * CC + cbase] = o;
  }
  // rb fragment-order u64 stores (proven mapping)
  unsigned long long* rb64 = (unsigned long long*)(ws + OFF_RB);
  int j0r = i0 + r0;                          // j0r&7 in {0,4}
  #pragma unroll
  for (int cc = 0; cc < 4; cc++) {
    int c = cbase + cc;
    unsigned long long v = 0;
    #pragma unroll
    for (int rr = 0; rr < 4; rr++) {
      unsigned u = __float_as_uint(acc[rr][cc]);
      u = (u + 0x7fffu + ((u >> 16) & 1u)) >> 16;   // RNE to bf16
      v |= (unsigned long long)u << (16 * rr);
    }
    int us = (((j0r >> 5) * 16 + (c >> 4)) * 64 + (((j0r >> 3) & 3) * 16 + (c & 15))) * 8 + (j0r & 7);
    rb64[us >> 2] = v;                        // us % 4 == 0
  }
  // s partials: this block's 64-col contribution, shuffle-reduced over tx
  f32x4 wc4 = *(const f32x4*)&wcv[cbase];
  float sd[4];
  #pragma unroll
  for (int rr = 0; rr < 4; rr++) {
    sd[rr] = acc[rr][0]*wc4[0] + acc[rr][1]*wc4[1] + acc[rr][2]*wc4[2] + acc[rr][3]*wc4[3];
    #pragma unroll
    for (int m = 1; m < 16; m <<= 1) sd[rr] += __shfl_xor(sd[rr], m, 64);
  }
  if (tx == 0) {
    #pragma unroll
    for (int rr = 0; rr < 4; rr++)
      ws[OFF_SP + colblk * NN + j0r + rr] = sd[rr];
  }
}

// ---------------- kernel 3: s2 = (sum of 4 partials) * log2e ----------------
__global__ __launch_bounds__(256) void k_s2(float* __restrict__ ws) {
  int row = blockIdx.x * 256 + threadIdx.x;   // 32 blocks
  float s = ws[OFF_SP + row] + ws[OFF_SP + NN + row]
          + ws[OFF_SP + 2 * NN + row] + ws[OFF_SP + 3 * NN + row];
  ws[OFF_S2 + row] = s * LOG2E;
}

// ---------------- kernel 4: main pairwise flash-style kernel ----------------
// R11 base (512 blocks x 256 thr, 4 waves x 32 rows, depth-2 vmcnt(4)), with
// the consume phase split: BLOAD issues all 16 ds_read_b128 into regs FIRST,
// SIGMOID(J+1) VALU runs while reads are in flight, MFMA_APPLY consumes.

#define STAGE(BUF, IT) { \
  const char* gb_ = rbase + (size_t)(IT) * 16384 + w * 1024 + l * 16; \
  _Pragma("unroll") \
  for (int q_ = 0; q_ < 4; q_++) \
    __builtin_amdgcn_global_load_lds( \
      (const __attribute__((address_space(1))) void*)(gb_ + q_ * 4096), \
      (__attribute__((address_space(3))) void*)&ldsb[(BUF) * 16384 + w * 1024 + q_ * 4096], \
      16, 0, 0); }

#define WAITBAR4 { asm volatile("s_waitcnt vmcnt(4)" ::: "memory"); \
  __builtin_amdgcn_s_barrier(); \
  __builtin_amdgcn_sched_barrier(0); }

#define WAITBAR0 { asm volatile("s_waitcnt vmcnt(0)" ::: "memory"); \
  __builtin_amdgcn_s_barrier(); \
  __builtin_amdgcn_sched_barrier(0); }

#define SB0 __builtin_amdgcn_sched_barrier(0);

#define SIGMOID(IT, AFA, AFB) { \
  f32x4 sj0_ = *(const f32x4*)&s2l[(IT) * 32 + g * 8]; \
  f32x4 sj1_ = *(const f32x4*)&s2l[(IT) * 32 + g * 8 + 4]; \
  _Pragma("unroll") \
  for (int t_ = 0; t_ < 8; t_++) { \
    float sj_ = (t_ < 4) ? sj0_[t_] : sj1_[t_ - 4]; \
    float eA_, eB_; \
    asm("v_exp_f32 %0, %1" : "=v"(eA_) : "v"(negaA - sj_)); \
    asm("v_exp_f32 %0, %1" : "=v"(eB_) : "v"(negaB - sj_)); \
    float zA_ = __builtin_amdgcn_rcpf(1.0f + eA_); \
    float zB_ = __builtin_amdgcn_rcpf(1.0f + eB_); \
    (AFA)[t_] = (short)(__float_as_uint(zA_) >> 16); \
    (AFB)[t_] = (short)(__float_as_uint(zB_) >> 16); } }

#define BLOAD(BF, LP) { \
  _Pragma("unroll") \
  for (int ct_ = 0; ct_ < 16; ct_++) \
    BF[ct_] = *(const s16x8*)((LP) + ct_ * 1024 + l * 16); }

#define MFMA_APPLY(AFA, AFB, BF) { \
  _Pragma("unroll") \
  for (int ct_ = 0; ct_ < 16; ct_++) { \
    accA[ct_] = __builtin_amdgcn_mfma_f32_16x16x32_bf16(AFA, BF[ct_], accA[ct_], 0, 0, 0); \
    accB[ct_] = __builtin_amdgcn_mfma_f32_16x16x32_bf16(AFB, BF[ct_], accB[ct_], 0, 0, 0); } \
  acc1A = __builtin_amdgcn_mfma_f32_16x16x32_bf16(AFA, ones, acc1A, 0, 0, 0); \
  acc1B = __builtin_amdgcn_mfma_f32_16x16x32_bf16(AFB, ones, acc1B, 0, 0, 0); }

__global__ __launch_bounds__(256, 2) void k_main(float* __restrict__ ws) {
  __shared__ char ldsb[3 * 16384];
  __shared__ float s2l[1024];
  int blk = blockIdx.x;
  int rt = blk >> 3, h = blk & 7;            // h == XCD id -> per-XCD L2 locality
  int tid = threadIdx.x;
  int w = tid >> 6, l = tid & 63;
  int lr = l & 15, g = l >> 4;
  int iw = rt * 128 + w * 32;                // wave's 32-row strip (2 frags of 16)
  float c02 = ws[OFF_C0 + 1];
  float negaA = -(ws[OFF_S2 + iw + lr] + c02);
  float negaB = -(ws[OFF_S2 + iw + 16 + lr] + c02);

  // stage this split's s2 slice to LDS (keeps loop VMEM = global_load_lds only)
  const float* s2p = ws + OFF_S2 + h * JR;
  *(f32x4*)&s2l[tid * 4] = *(const f32x4*)(s2p + tid * 4);
  __syncthreads();

  f32x4 accA[16], accB[16], acc1A, acc1B;
  #pragma unroll
  for (int i = 0; i < 16; i++) { accA[i] = (f32x4)(0.f); accB[i] = (f32x4)(0.f); }
  acc1A = (f32x4)(0.f); acc1B = (f32x4)(0.f);
  s16x8 ones;
  #pragma unroll
  for (int t = 0; t < 8; t++) ones[t] = (short)0x3F80;   // bf16 1.0

  const char* rbase = (const char*)(ws + OFF_RB) + (size_t)h * (JR * CC * 2);

  STAGE(0, 0);
  STAGE(1, 1);
  s16x8 afA0, afB0, afA1, afB1;
  s16x8 bf[16];
  SIGMOID(0, afA0, afB0);

  int sA = 0;                                // J%3
  #pragma unroll 1
  for (int J = 0; J < NITER - 2; J += 2) {
    int sB = sA + 1; if (sB == 3) sB = 0;    // (J+1)%3
    int sC = sB + 1; if (sC == 3) sC = 0;    // (J+2)%3

    WAITBAR4;                                // buf J ready (all waves)
    STAGE(sC, J + 2);
    SB0;
    BLOAD(bf, ldsb + sA * 16384);            // issue 16 ds_reads early
    SB0;
    SIGMOID(J + 1, afA1, afB1);              // VALU hides ds latency
    MFMA_APPLY(afA0, afB0, bf);

    WAITBAR4;                                // buf J+1 ready
    STAGE(sA, J + 3);                        // (J+3)%3 == J%3
    SB0;
    BLOAD(bf, ldsb + sB * 16384);
    SB0;
    SIGMOID(J + 2, afA0, afB0);
    MFMA_APPLY(afA1, afB1, bf);

    sA = sC;
  }
  {                                          // tail: chunks NITER-2, NITER-1
    int sB = sA + 1; if (sB == 3) sB = 0;
    WAITBAR4;                                // chunk NITER-2 ready
    BLOAD(bf, ldsb + sA * 16384);
    SB0;
    SIGMOID(NITER - 1, afA1, afB1);
    MFMA_APPLY(afA0, afB0, bf);
    WAITBAR0;                                // chunk NITER-1 ready
    BLOAD(bf, ldsb + sB * 16384);
    MFMA_APPLY(afA1, afB1, bf);
  }

  // row-sums of Z from ones-MFMA (all cols equal; lr==0 lanes write 4 rows each)
  if (lr == 0) {
    #pragma unroll
    for (int q = 0; q < 4; q++) {
      ws[OFF_SS + h * NN + iw + g * 4 + q] = acc1A[q];
      ws[OFF_SS + h * NN + iw + 16 + g * 4 + q] = acc1B[q];
    }
  }
  // V partials (bf16). C/D layout: col = lane&15, row = (lane>>4)*4 + reg
  unsigned short* Vb = (unsigned short*)(ws + OFF_V);
  size_t vbase = (size_t)h * (NN * CC);
  #pragma unroll
  for (int ct = 0; ct < 16; ct++) {
    #pragma unroll
    for (int q = 0; q < 4; q++) {
      unsigned uA = __float_as_uint(accA[ct][q]);
      uA = (uA + 0x7fffu + ((uA >> 16) & 1u)) >> 16;
      Vb[vbase + (size_t)(iw + g * 4 + q) * CC + ct * 16 + lr] = (unsigned short)uA;
      unsigned uB = __float_as_uint(accB[ct][q]);
      uB = (uB + 0x7fffu + ((uB >> 16) & 1u)) >> 16;
      Vb[vbase + (size_t)(iw + 16 + g * 4 + q) * CC + ct * 16 + lr] = (unsigned short)uB;
    }
  }
}

// ---------------- kernel 5: epilogue out = (r+b)*S/N + sum_h V_h/N ----------
__global__ __launch_bounds__(256) void k_epi(const float* __restrict__ br,
                                             const float* __restrict__ ws,
                                             float* __restrict__ out) {
  int idx = blockIdx.x * 256 + threadIdx.x;   // N*C/8 = 262144 threads
  int i = idx >> 5, c8 = (idx & 31) * 8;
  float S = 0.f;
  #pragma unroll
  for (int p = 0; p < NSPLIT; p++) S += ws[OFF_SS + p * NN + i];
  float m = S * (1.0f / NN);
  float v[8] = {};
  const unsigned short* Vb = (const unsigned short*)(ws + OFF_V);
  #pragma unroll
  for (int p = 0; p < NSPLIT; p++) {
    s16x8 pv = *(const s16x8*)&Vb[(size_t)p * (NN * CC) + (size_t)i * CC + c8];
    #pragma unroll
    for (int t = 0; t < 8; t++)
      v[t] += __uint_as_float(((unsigned)(unsigned short)pv[t]) << 16);
  }
  f32x4 r0 = *(const f32x4*)&ws[OFF_R + (size_t)i * CC + c8];
  f32x4 r1 = *(const f32x4*)&ws[OFF_R + (size_t)i * CC + c8 + 4];
  f32x4 b0 = *(const f32x4*)&br[c8];
  f32x4 b1 = *(const f32x4*)&br[c8 + 4];
  f32x4 o0, o1;
  #pragma unroll
  for (int t = 0; t < 4; t++) {
    o0[t] = (r0[t] + b0[t]) * m + v[t] * (1.0f / NN);
    o1[t] = (r1[t] + b1[t]) * m + v[t + 4] * (1.0f / NN);
  }
  *(f32x4*)&out[(size_t)i * CC + c8] = o0;
  *(f32x4*)&out[(size_t)i * CC + c8 + 4] = o1;
}

extern "C" void kernel_launch(void* const* d_in, const int* in_sizes, int n_in,
                              void* d_out, int out_size, void* d_ws, size_t ws_size,
                              hipStream_t stream) {
  const float* x  = (const float*)d_in[0];
  const float* w  = (const float*)d_in[1];
  const float* br = (const float*)d_in[2];
  const float* wc = (const float*)d_in[3];
  const float* bc = (const float*)d_in[4];
  float* ws = (float*)d_ws;
  float* out = (float*)d_out;
  (void)in_sizes; (void)n_in; (void)out_size; (void)ws_size;

  k_prep<<<256, 256, 0, stream>>>(w, br, wc, bc, ws);
  k_r<<<512, 256, 0, stream>>>(x, wc, ws);
  k_s2<<<32, 256, 0, stream>>>(ws);
  k_main<<<512, 256, 0, stream>>>(ws);
  k_epi<<<1024, 256, 0, stream>>>(br, ws, out);
}

// Round 19
// 80.199 us; speedup vs baseline: 1.2321x; 1.0553x over previous
//
#include <hip/hip_runtime.h>
#include <hip/hip_bf16.h>
#include <stdint.h>

#define NN 8192
#define CC 256
#define NSPLIT 8                          // j-splits; h = blk&7 == XCD id
#define JR (NN / NSPLIT)                  // 1024 j per split
#define NITER (JR / 32)                   // 32 chunks of 32 j

typedef float f32x4 __attribute__((ext_vector_type(4)));
typedef float f32x2 __attribute__((ext_vector_type(2)));
typedef short s16x8 __attribute__((ext_vector_type(8)));

#define LOG2E 1.4426950408889634f

// ---- workspace layout (float offsets). rb now fp8 (2 MB). ----
#define OFF_WT  0                                 // 256*256 transposed w_reduce
#define OFF_R   (OFF_WT + CC*CC)                  // N*C fp32 r
#define OFF_S2  (OFF_R + NN*CC)                   // N fp32 s*log2e
#define OFF_C0  (OFF_S2 + NN)                     // [0]=c0, [1]=c0*log2e
#define OFF_SS  (OFF_C0 + 16)                     // NSPLIT*N fp32 partial row-sums of Z
#define OFF_SP  (OFF_SS + NSPLIT*NN)              // 4*N fp32 s partials (per colblk)
#define OFF_V   (OFF_SP + 4*NN)                   // NSPLIT*N*C bf16 partial Z@r (ushort)
#define OFF_RB  (OFF_V + (NSPLIT*NN*CC)/2)        // N*C fp8 e4m3 fragment-ordered r

// ---------------- kernel 1: transpose Wr + compute c0 ----------------
__global__ __launch_bounds__(256) void k_prep(const float* __restrict__ w,
                                              const float* __restrict__ br,
                                              const float* __restrict__ wcv,
                                              const float* __restrict__ bc,
                                              float* __restrict__ ws) {
  int k = blockIdx.x, c = threadIdx.x;
  ws[OFF_WT + k * CC + c] = w[c * CC + k];   // wT[k][c] = w[c][k]
  if (blockIdx.x == 0 && threadIdx.x < 64) {
    int lane = threadIdx.x;
    f32x4 b4 = *(const f32x4*)&br[lane * 4];
    f32x4 w4 = *(const f32x4*)&wcv[lane * 4];
    float d = b4[0]*w4[0] + b4[1]*w4[1] + b4[2]*w4[2] + b4[3]*w4[3];
    #pragma unroll
    for (int m = 32; m >= 1; m >>= 1) d += __shfl_xor(d, m, 64);
    if (lane == 0) { ws[OFF_C0] = d + bc[0]; ws[OFF_C0 + 1] = (d + bc[0]) * LOG2E; }
  }
}

// ------- kernel 2: r = x @ Wr^T + rb (fp8 frag-order u32 stores) + s partials --
__global__ __launch_bounds__(256) void k_r(const float* __restrict__ x,
                                           const float* __restrict__ wcv,
                                           float* __restrict__ ws) {
  __shared__ float xs[64][260];
  int bi = blockIdx.x;
  int rowblk = bi >> 2, colblk = bi & 3;
  int tid = threadIdx.x;
  int i0 = rowblk * 64;
  for (int t = tid; t < 64 * 64; t += 256) {
    int rr = t >> 6, c4 = t & 63;
    *(f32x4*)&xs[rr][c4 * 4] = *(const f32x4*)&x[(i0 + rr) * CC + c4 * 4];
  }
  __syncthreads();
  int tx = tid & 15, ty = tid >> 4;
  int cbase = colblk * 64 + tx * 4;
  int r0 = ty * 4;
  float acc[4][4] = {};
  const float* wt = ws + OFF_WT;
  for (int k = 0; k < CC; k += 2) {
    f32x4 wv0 = *(const f32x4*)&wt[k * CC + cbase];
    f32x4 wv1 = *(const f32x4*)&wt[(k + 1) * CC + cbase];
    f32x2 xv[4];
    #pragma unroll
    for (int rr = 0; rr < 4; rr++) xv[rr] = *(const f32x2*)&xs[r0 + rr][k];
    #pragma unroll
    for (int rr = 0; rr < 4; rr++)
      #pragma unroll
      for (int cc = 0; cc < 4; cc++)
        acc[rr][cc] = fmaf(xv[rr][1], wv1[cc], fmaf(xv[rr][0], wv0[cc], acc[rr][cc]));
  }
  #pragma unroll
  for (int rr = 0; rr < 4; rr++) {
    f32x4 o = {acc[rr][0], acc[rr][1], acc[rr][2], acc[rr][3]};
    *(f32x4*)&ws[OFF_R + (size_t)(i0 + r0 + rr) * CC + cbase] = o;
  }
  // rb fragment-order fp8 stores: 4 consecutive j-rows (one thread) share a
  // lane entry with k-runs 0..3 or 4..7 -> one u32 per column (same index
  // formula as the proven u64/bf16 mapping, now in bytes).
  unsigned* rb32 = (unsigned*)(ws + OFF_RB);
  int j0r = i0 + r0;                          // j0r&7 in {0,4}
  #pragma unroll
  for (int cc = 0; cc < 4; cc++) {
    int c = cbase + cc;
    unsigned pk = 0;
    pk = __builtin_amdgcn_cvt_pk_fp8_f32(acc[0][cc], acc[1][cc], (int)pk, false);
    pk = __builtin_amdgcn_cvt_pk_fp8_f32(acc[2][cc], acc[3][cc], (int)pk, true);
    int us = (((j0r >> 5) * 16 + (c >> 4)) * 64 + (((j0r >> 3) & 3) * 16 + (c & 15))) * 8 + (j0r & 7);
    rb32[us >> 2] = pk;                       // us % 4 == 0 (byte offsets)
  }
  // s partials: this block's 64-col contribution, shuffle-reduced over tx
  f32x4 wc4 = *(const f32x4*)&wcv[cbase];
  float sd[4];
  #pragma unroll
  for (int rr = 0; rr < 4; rr++) {
    sd[rr] = acc[rr][0]*wc4[0] + acc[rr][1]*wc4[1] + acc[rr][2]*wc4[2] + acc[rr][3]*wc4[3];
    #pragma unroll
    for (int m = 1; m < 16; m <<= 1) sd[rr] += __shfl_xor(sd[rr], m, 64);
  }
  if (tx == 0) {
    #pragma unroll
    for (int rr = 0; rr < 4; rr++)
      ws[OFF_SP + colblk * NN + j0r + rr] = sd[rr];
  }
}

// ---------------- kernel 3: s2 = (sum of 4 partials) * log2e ----------------
__global__ __launch_bounds__(256) void k_s2(float* __restrict__ ws) {
  int row = blockIdx.x * 256 + threadIdx.x;   // 32 blocks
  float s = ws[OFF_SP + row] + ws[OFF_SP + NN + row]
          + ws[OFF_SP + 2 * NN + row] + ws[OFF_SP + 3 * NN + row];
  ws[OFF_S2 + row] = s * LOG2E;
}

// ---------------- kernel 4: main pairwise flash-style kernel (fp8 B) --------
// R18 schedule, fp8 operands: B chunk = 8 KB (ds_read_b64/frag), stage = 2
// global_load_lds per buffer (vmcnt(2) counted wait), Z packed to e4m3 via
// cvt_pk_fp8. MFMA = f32_16x16x32_fp8_fp8 (same shape/rate as bf16).

#define STAGE(BUF, IT) { \
  const char* gb_ = rbase + (size_t)(IT) * 8192 + w * 1024 + l * 16; \
  _Pragma("unroll") \
  for (int q_ = 0; q_ < 2; q_++) \
    __builtin_amdgcn_global_load_lds( \
      (const __attribute__((address_space(1))) void*)(gb_ + q_ * 4096), \
      (__attribute__((address_space(3))) void*)&ldsb[(BUF) * 8192 + w * 1024 + q_ * 4096], \
      16, 0, 0); }

#define WAITBAR2 { asm volatile("s_waitcnt vmcnt(2)" ::: "memory"); \
  __builtin_amdgcn_s_barrier(); \
  __builtin_amdgcn_sched_barrier(0); }

#define WAITBAR0 { asm volatile("s_waitcnt vmcnt(0)" ::: "memory"); \
  __builtin_amdgcn_s_barrier(); \
  __builtin_amdgcn_sched_barrier(0); }

#define SB0 __builtin_amdgcn_sched_barrier(0);

#define SIGMOID(IT, AFA, AFB) { \
  f32x4 sj0_ = *(const f32x4*)&s2l[(IT) * 32 + g * 8]; \
  f32x4 sj1_ = *(const f32x4*)&s2l[(IT) * 32 + g * 8 + 4]; \
  float zA_[8], zB_[8]; \
  _Pragma("unroll") \
  for (int t_ = 0; t_ < 8; t_++) { \
    float sj_ = (t_ < 4) ? sj0_[t_] : sj1_[t_ - 4]; \
    float eA_, eB_; \
    asm("v_exp_f32 %0, %1" : "=v"(eA_) : "v"(negaA - sj_)); \
    asm("v_exp_f32 %0, %1" : "=v"(eB_) : "v"(negaB - sj_)); \
    zA_[t_] = __builtin_amdgcn_rcpf(1.0f + eA_); \
    zB_[t_] = __builtin_amdgcn_rcpf(1.0f + eB_); } \
  unsigned loA_ = 0, hiA_ = 0, loB_ = 0, hiB_ = 0; \
  loA_ = __builtin_amdgcn_cvt_pk_fp8_f32(zA_[0], zA_[1], (int)loA_, false); \
  loA_ = __builtin_amdgcn_cvt_pk_fp8_f32(zA_[2], zA_[3], (int)loA_, true); \
  hiA_ = __builtin_amdgcn_cvt_pk_fp8_f32(zA_[4], zA_[5], (int)hiA_, false); \
  hiA_ = __builtin_amdgcn_cvt_pk_fp8_f32(zA_[6], zA_[7], (int)hiA_, true); \
  loB_ = __builtin_amdgcn_cvt_pk_fp8_f32(zB_[0], zB_[1], (int)loB_, false); \
  loB_ = __builtin_amdgcn_cvt_pk_fp8_f32(zB_[2], zB_[3], (int)loB_, true); \
  hiB_ = __builtin_amdgcn_cvt_pk_fp8_f32(zB_[4], zB_[5], (int)hiB_, false); \
  hiB_ = __builtin_amdgcn_cvt_pk_fp8_f32(zB_[6], zB_[7], (int)hiB_, true); \
  AFA = (long)(((unsigned long long)hiA_ << 32) | loA_); \
  AFB = (long)(((unsigned long long)hiB_ << 32) | loB_); }

#define BLOAD(BF, LP) { \
  _Pragma("unroll") \
  for (int ct_ = 0; ct_ < 16; ct_++) \
    BF[ct_] = *(const long*)((LP) + ct_ * 512 + l * 8); }

#define MFMA_APPLY(AFA, AFB, BF) { \
  _Pragma("unroll") \
  for (int ct_ = 0; ct_ < 16; ct_++) { \
    accA[ct_] = __builtin_amdgcn_mfma_f32_16x16x32_fp8_fp8(AFA, BF[ct_], accA[ct_], 0, 0, 0); \
    accB[ct_] = __builtin_amdgcn_mfma_f32_16x16x32_fp8_fp8(AFB, BF[ct_], accB[ct_], 0, 0, 0); } \
  acc1A = __builtin_amdgcn_mfma_f32_16x16x32_fp8_fp8(AFA, ones, acc1A, 0, 0, 0); \
  acc1B = __builtin_amdgcn_mfma_f32_16x16x32_fp8_fp8(AFB, ones, acc1B, 0, 0, 0); }

__global__ __launch_bounds__(256, 2) void k_main(float* __restrict__ ws) {
  __shared__ char ldsb[3 * 8192];
  __shared__ float s2l[1024];
  int blk = blockIdx.x;
  int rt = blk >> 3, h = blk & 7;            // h == XCD id -> per-XCD L2 locality
  int tid = threadIdx.x;
  int w = tid >> 6, l = tid & 63;
  int lr = l & 15, g = l >> 4;
  int iw = rt * 128 + w * 32;                // wave's 32-row strip (2 frags of 16)
  float c02 = ws[OFF_C0 + 1];
  float negaA = -(ws[OFF_S2 + iw + lr] + c02);
  float negaB = -(ws[OFF_S2 + iw + 16 + lr] + c02);

  // stage this split's s2 slice to LDS (keeps loop VMEM = global_load_lds only)
  const float* s2p = ws + OFF_S2 + h * JR;
  *(f32x4*)&s2l[tid * 4] = *(const f32x4*)(s2p + tid * 4);
  __syncthreads();

  f32x4 accA[16], accB[16], acc1A, acc1B;
  #pragma unroll
  for (int i = 0; i < 16; i++) { accA[i] = (f32x4)(0.f); accB[i] = (f32x4)(0.f); }
  acc1A = (f32x4)(0.f); acc1B = (f32x4)(0.f);
  const long ones = 0x3838383838383838LL;    // fp8 e4m3 1.0 x8

  const char* rbase = (const char*)(ws + OFF_RB) + (size_t)h * (JR * CC);

  STAGE(0, 0);
  STAGE(1, 1);
  long afA0, afB0, afA1, afB1;
  long bf[16];
  SIGMOID(0, afA0, afB0);

  int sA = 0;                                // J%3
  #pragma unroll 1
  for (int J = 0; J < NITER - 2; J += 2) {
    int sB = sA + 1; if (sB == 3) sB = 0;    // (J+1)%3
    int sC = sB + 1; if (sC == 3) sC = 0;    // (J+2)%3

    WAITBAR2;                                // buf J ready (all waves)
    STAGE(sC, J + 2);
    SB0;
    BLOAD(bf, ldsb + sA * 8192);             // issue 16 ds_read_b64 early
    SB0;
    SIGMOID(J + 1, afA1, afB1);              // VALU hides ds latency
    MFMA_APPLY(afA0, afB0, bf);

    WAITBAR2;                                // buf J+1 ready
    STAGE(sA, J + 3);                        // (J+3)%3 == J%3
    SB0;
    BLOAD(bf, ldsb + sB * 8192);
    SB0;
    SIGMOID(J + 2, afA0, afB0);
    MFMA_APPLY(afA1, afB1, bf);

    sA = sC;
  }
  {                                          // tail: chunks NITER-2, NITER-1
    int sB = sA + 1; if (sB == 3) sB = 0;
    WAITBAR2;                                // chunk NITER-2 ready
    BLOAD(bf, ldsb + sA * 8192);
    SB0;
    SIGMOID(NITER - 1, afA1, afB1);
    MFMA_APPLY(afA0, afB0, bf);
    WAITBAR0;                                // chunk NITER-1 ready
    BLOAD(bf, ldsb + sB * 8192);
    MFMA_APPLY(afA1, afB1, bf);
  }

  // row-sums of Z from ones-MFMA (all cols equal; lr==0 lanes write 4 rows each)
  if (lr == 0) {
    #pragma unroll
    for (int q = 0; q < 4; q++) {
      ws[OFF_SS + h * NN + iw + g * 4 + q] = acc1A[q];
      ws[OFF_SS + h * NN + iw + 16 + g * 4 + q] = acc1B[q];
    }
  }
  // V partials (bf16). C/D layout: col = lane&15, row = (lane>>4)*4 + reg
  unsigned short* Vb = (unsigned short*)(ws + OFF_V);
  size_t vbase = (size_t)h * (NN * CC);
  #pragma unroll
  for (int ct = 0; ct < 16; ct++) {
    #pragma unroll
    for (int q = 0; q < 4; q++) {
      unsigned uA = __float_as_uint(accA[ct][q]);
      uA = (uA + 0x7fffu + ((uA >> 16) & 1u)) >> 16;
      Vb[vbase + (size_t)(iw + g * 4 + q) * CC + ct * 16 + lr] = (unsigned short)uA;
      unsigned uB = __float_as_uint(accB[ct][q]);
      uB = (uB + 0x7fffu + ((uB >> 16) & 1u)) >> 16;
      Vb[vbase + (size_t)(iw + 16 + g * 4 + q) * CC + ct * 16 + lr] = (unsigned short)uB;
    }
  }
}

// ---------------- kernel 5: epilogue out = (r+b)*S/N + sum_h V_h/N ----------
__global__ __launch_bounds__(256) void k_epi(const float* __restrict__ br,
                                             const float* __restrict__ ws,
                                             float* __restrict__ out) {
  int idx = blockIdx.x * 256 + threadIdx.x;   // N*C/8 = 262144 threads
  int i = idx >> 5, c8 = (idx & 31) * 8;
  float S = 0.f;
  #pragma unroll
  for (int p = 0; p < NSPLIT; p++) S += ws[OFF_SS + p * NN + i];
  float m = S * (1.0f / NN);
  float v[8] = {};
  const unsigned short* Vb = (const unsigned short*)(ws + OFF_V);
  #pragma unroll
  for (int p = 0; p < NSPLIT; p++) {
    s16x8 pv = *(const s16x8*)&Vb[(size_t)p * (NN * CC) + (size_t)i * CC + c8];
    #pragma unroll
    for (int t = 0; t < 8; t++)
      v[t] += __uint_as_float(((unsigned)(unsigned short)pv[t]) << 16);
  }
  f32x4 r0 = *(const f32x4*)&ws[OFF_R + (size_t)i * CC + c8];
  f32x4 r1 = *(const f32x4*)&ws[OFF_R + (size_t)i * CC + c8 + 4];
  f32x4 b0 = *(const f32x4*)&br[c8];
  f32x4 b1 = *(const f32x4*)&br[c8 + 4];
  f32x4 o0, o1;
  #pragma unroll
  for (int t = 0; t < 4; t++) {
    o0[t] = (r0[t] + b0[t]) * m + v[t] * (1.0f / NN);
    o1[t] = (r1[t] + b1[t]) * m + v[t + 4] * (1.0f / NN);
  }
  *(f32x4*)&out[(size_t)i * CC + c8] = o0;
  *(f32x4*)&out[(size_t)i * CC + c8 + 4] = o1;
}

extern "C" void kernel_launch(void* const* d_in, const int* in_sizes, int n_in,
                              void* d_out, int out_size, void* d_ws, size_t ws_size,
                              hipStream_t stream) {
  const float* x  = (const float*)d_in[0];
  const float* w  = (const float*)d_in[1];
  const float* br = (const float*)d_in[2];
  const float* wc = (const float*)d_in[3];
  const float* bc = (const float*)d_in[4];
  float* ws = (float*)d_ws;
  float* out = (float*)d_out;
  (void)in_sizes; (void)n_in; (void)out_size; (void)ws_size;

  k_prep<<<256, 256, 0, stream>>>(w, br, wc, bc, ws);
  k_r<<<512, 256, 0, stream>>>(x, wc, ws);
  k_s2<<<32, 256, 0, stream>>>(ws);
  k_main<<<512, 256, 0, stream>>>(ws);
  k_epi<<<1024, 256, 0, stream>>>(br, ws, out);
}